// Round 1
// baseline (634.510 us; speedup 1.0000x reference)
//
#include <hip/hip_runtime.h>

#define N_NODES   50000
#define N_EDGES   800000
#define NODE_DIM  128
#define HIDDEN    256
#define LATENT    128
#define COND      5

// ---------------- CSR build ----------------

__global__ void hist_kernel(const int* __restrict__ dst, int* __restrict__ deg) {
    int e = blockIdx.x * blockDim.x + threadIdx.x;
    if (e < N_EDGES) atomicAdd(&deg[dst[e]], 1);
}

// single block, 1024 threads: exclusive scan of deg[50000] -> offsets[50001], copy to cursor
__global__ void scan_kernel(const int* __restrict__ deg, int* __restrict__ offsets,
                            int* __restrict__ cursor) {
    __shared__ int sums[1024];
    const int C = (N_NODES + 1023) / 1024;  // 49
    int t = threadIdx.x;
    int begin = t * C;
    int end   = begin + C < N_NODES ? begin + C : N_NODES;
    int s = 0;
    for (int i = begin; i < end; ++i) s += deg[i];
    sums[t] = s;
    __syncthreads();
    // Hillis-Steele inclusive scan over 1024 partials
    for (int off = 1; off < 1024; off <<= 1) {
        int v = (t >= off) ? sums[t - off] : 0;
        __syncthreads();
        sums[t] += v;
        __syncthreads();
    }
    int running = (t == 0) ? 0 : sums[t - 1];
    for (int i = begin; i < end; ++i) {
        offsets[i] = running;
        cursor[i]  = running;
        running += deg[i];
    }
    if (t == 1023) offsets[N_NODES] = sums[1023];
}

__global__ void scatter_kernel(const int* __restrict__ src, const int* __restrict__ dst,
                               int* __restrict__ cursor, int* __restrict__ csr_src) {
    int e = blockIdx.x * blockDim.x + threadIdx.x;
    if (e < N_EDGES) {
        int pos = atomicAdd(&cursor[dst[e]], 1);
        csr_src[pos] = src[e];
    }
}

// ---------------- aggregation: one wave per node ----------------

template <int D>
__global__ void agg_kernel(const float* __restrict__ x, const int* __restrict__ offsets,
                           const int* __restrict__ csr_src, float* __restrict__ agg) {
    int gw   = (blockIdx.x * blockDim.x + threadIdx.x) >> 6;  // global wave = node
    int lane = threadIdx.x & 63;
    if (gw >= N_NODES) return;
    int j0 = offsets[gw], j1 = offsets[gw + 1];
    constexpr int V = D / 64;  // 2 (D=128) or 4 (D=256)
    float acc[V];
#pragma unroll
    for (int i = 0; i < V; ++i) acc[i] = 0.f;
    for (int j = j0; j < j1; ++j) {
        int s = csr_src[j];
        const float* row = x + (size_t)s * D + lane * V;
        if constexpr (V == 2) {
            float2 u = *reinterpret_cast<const float2*>(row);
            acc[0] += u.x; acc[1] += u.y;
        } else {
            float4 u = *reinterpret_cast<const float4*>(row);
            acc[0] += u.x; acc[1] += u.y; acc[2] += u.z; acc[3] += u.w;
        }
    }
    float* o = agg + (size_t)gw * D + lane * V;
    if constexpr (V == 2) {
        *reinterpret_cast<float2*>(o) = make_float2(acc[0], acc[1]);
    } else {
        *reinterpret_cast<float4*>(o) = make_float4(acc[0], acc[1], acc[2], acc[3]);
    }
}

// ---------------- GEMM1: x1 = relu(agg1 @ W1 + b1), [50000,128]x[128,256] ----------------
// 16 rows/tile, 256 threads, 4x4 micro-tile per thread. A-tile in LDS (broadcast reads).

__global__ __launch_bounds__(256) void gemm1_kernel(const float* __restrict__ A,
                                                    const float* __restrict__ W,
                                                    const float* __restrict__ b,
                                                    float* __restrict__ X) {
    __shared__ float As[16][NODE_DIM + 4];  // +4 keeps float4 stores 16B aligned
    const int t    = threadIdx.x;
    const int row0 = blockIdx.x * 16;

    // stage 16x128 A-tile: 512 float4, 2 per thread
#pragma unroll
    for (int it = 0; it < 2; ++it) {
        int idx = t + it * 256;          // 0..511
        int r   = idx >> 5;              // 0..15
        int kq  = idx & 31;              // 0..31
        float4 v = *reinterpret_cast<const float4*>(&A[(size_t)(row0 + r) * NODE_DIM + kq * 4]);
        *reinterpret_cast<float4*>(&As[r][kq * 4]) = v;
    }
    __syncthreads();

    const int tx = t & 63, ty = t >> 6;
    const int j0 = tx * 4;
    const int r0 = ty * 4;
    float acc[4][4] = {};

#pragma unroll 4
    for (int k = 0; k < NODE_DIM; ++k) {
        float4 w = *reinterpret_cast<const float4*>(&W[k * HIDDEN + j0]);
        float a0 = As[r0 + 0][k], a1 = As[r0 + 1][k], a2 = As[r0 + 2][k], a3 = As[r0 + 3][k];
        acc[0][0] += a0 * w.x; acc[0][1] += a0 * w.y; acc[0][2] += a0 * w.z; acc[0][3] += a0 * w.w;
        acc[1][0] += a1 * w.x; acc[1][1] += a1 * w.y; acc[1][2] += a1 * w.z; acc[1][3] += a1 * w.w;
        acc[2][0] += a2 * w.x; acc[2][1] += a2 * w.y; acc[2][2] += a2 * w.z; acc[2][3] += a2 * w.w;
        acc[3][0] += a3 * w.x; acc[3][1] += a3 * w.y; acc[3][2] += a3 * w.z; acc[3][3] += a3 * w.w;
    }

    float4 bias = *reinterpret_cast<const float4*>(&b[j0]);
#pragma unroll
    for (int i = 0; i < 4; ++i) {
        float4 o;
        o.x = fmaxf(acc[i][0] + bias.x, 0.f);
        o.y = fmaxf(acc[i][1] + bias.y, 0.f);
        o.z = fmaxf(acc[i][2] + bias.z, 0.f);
        o.w = fmaxf(acc[i][3] + bias.w, 0.f);
        *reinterpret_cast<float4*>(&X[(size_t)(row0 + r0 + i) * HIDDEN + j0]) = o;
    }
}

// ---------------- GEMM2 + mean-pool (x2 never stored) ----------------
// pooled_sum[j] += sum over rows of relu(agg2 @ W2 + b2)[.,j]; grid-stride over tiles.

__global__ __launch_bounds__(256) void gemm2_pool_kernel(const float* __restrict__ A,
                                                         const float* __restrict__ W,
                                                         const float* __restrict__ b,
                                                         float* __restrict__ pooled) {
    __shared__ float As[16][HIDDEN + 4];
    __shared__ float red[4][HIDDEN];
    const int t  = threadIdx.x;
    const int tx = t & 63, ty = t >> 6;
    const int j0 = tx * 4;
    const int r0 = ty * 4;
    const int ntiles = N_NODES / 16;  // 3125

    float4 bias = *reinterpret_cast<const float4*>(&b[j0]);
    float cs[4] = {0.f, 0.f, 0.f, 0.f};

    for (int tile = blockIdx.x; tile < ntiles; tile += gridDim.x) {
        const int row0 = tile * 16;
        // stage 16x256: 1024 float4, 4 per thread
#pragma unroll
        for (int it = 0; it < 4; ++it) {
            int idx = t + it * 256;      // 0..1023
            int r   = idx >> 6;          // 0..15
            int kq  = idx & 63;          // 0..63
            float4 v = *reinterpret_cast<const float4*>(&A[(size_t)(row0 + r) * HIDDEN + kq * 4]);
            *reinterpret_cast<float4*>(&As[r][kq * 4]) = v;
        }
        __syncthreads();

        float acc[4][4] = {};
#pragma unroll 4
        for (int k = 0; k < HIDDEN; ++k) {
            float4 w = *reinterpret_cast<const float4*>(&W[k * HIDDEN + j0]);
            float a0 = As[r0 + 0][k], a1 = As[r0 + 1][k], a2 = As[r0 + 2][k], a3 = As[r0 + 3][k];
            acc[0][0] += a0 * w.x; acc[0][1] += a0 * w.y; acc[0][2] += a0 * w.z; acc[0][3] += a0 * w.w;
            acc[1][0] += a1 * w.x; acc[1][1] += a1 * w.y; acc[1][2] += a1 * w.z; acc[1][3] += a1 * w.w;
            acc[2][0] += a2 * w.x; acc[2][1] += a2 * w.y; acc[2][2] += a2 * w.z; acc[2][3] += a2 * w.w;
            acc[3][0] += a3 * w.x; acc[3][1] += a3 * w.y; acc[3][2] += a3 * w.z; acc[3][3] += a3 * w.w;
        }
#pragma unroll
        for (int i = 0; i < 4; ++i) {
            cs[0] += fmaxf(acc[i][0] + bias.x, 0.f);
            cs[1] += fmaxf(acc[i][1] + bias.y, 0.f);
            cs[2] += fmaxf(acc[i][2] + bias.z, 0.f);
            cs[3] += fmaxf(acc[i][3] + bias.w, 0.f);
        }
        __syncthreads();  // before restaging As
    }

    // block-level reduce over ty groups, then one atomic per column
#pragma unroll
    for (int c = 0; c < 4; ++c) red[ty][j0 + c] = cs[c];
    __syncthreads();
    if (ty == 0) {
#pragma unroll
        for (int c = 0; c < 4; ++c) {
            float s = red[0][j0 + c] + red[1][j0 + c] + red[2][j0 + c] + red[3][j0 + c];
            atomicAdd(&pooled[j0 + c], s);
        }
    }
}

// ---------------- head MLP: h = relu([pooled/N, cond] @ Wfc + bfc); z = h @ Wm/Wl + b ----------------

__global__ void head_kernel(const float* __restrict__ pooled_sum, const float* __restrict__ cond,
                            const float* __restrict__ Wfc, const float* __restrict__ bfc,
                            const float* __restrict__ Wmean, const float* __restrict__ bmean,
                            const float* __restrict__ Wlogvar, const float* __restrict__ blogvar,
                            float* __restrict__ out) {
    __shared__ float v[HIDDEN + COND];
    __shared__ float h[LATENT];
    int t = threadIdx.x;
    if (t < HIDDEN) v[t] = pooled_sum[t] * (1.0f / N_NODES);
    if (t < COND) v[HIDDEN + t] = cond[t];
    __syncthreads();
    if (t < LATENT) {
        float s = bfc[t];
        for (int k = 0; k < HIDDEN + COND; ++k) s += v[k] * Wfc[k * LATENT + t];
        h[t] = fmaxf(s, 0.f);
    }
    __syncthreads();
    if (t < LATENT) {
        float s = bmean[t];
        for (int k = 0; k < LATENT; ++k) s += h[k] * Wmean[k * LATENT + t];
        out[t] = s;
    } else {
        int j = t - LATENT;
        float s = blogvar[j];
        for (int k = 0; k < LATENT; ++k) s += h[k] * Wlogvar[k * LATENT + j];
        out[LATENT + j] = s;
    }
}

// ---------------- launch ----------------

extern "C" void kernel_launch(void* const* d_in, const int* in_sizes, int n_in,
                              void* d_out, int out_size, void* d_ws, size_t ws_size,
                              hipStream_t stream) {
    const float* node_features = (const float*)d_in[0];
    const float* conditions    = (const float*)d_in[1];
    const int*   src           = (const int*)d_in[2];
    const int*   dst           = (const int*)d_in[3];
    const float* W1  = (const float*)d_in[4];
    const float* b1  = (const float*)d_in[5];
    const float* W2  = (const float*)d_in[6];
    const float* b2  = (const float*)d_in[7];
    const float* Wfc = (const float*)d_in[8];
    const float* bfc = (const float*)d_in[9];
    const float* Wmean   = (const float*)d_in[10];
    const float* bmean   = (const float*)d_in[11];
    const float* Wlogvar = (const float*)d_in[12];
    const float* blogvar = (const float*)d_in[13];
    float* out = (float*)d_out;

    // workspace layout (256B aligned slices)
    size_t o = 0;
    auto alloc = [&](size_t bytes) {
        void* p = (char*)d_ws + o;
        o += (bytes + 255) & ~(size_t)255;
        return p;
    };
    int* deg      = (int*)alloc((size_t)N_NODES * 4);
    int* offsets  = (int*)alloc((size_t)(N_NODES + 1) * 4);
    int* cursor   = (int*)alloc((size_t)N_NODES * 4);
    int* csr_src  = (int*)alloc((size_t)N_EDGES * 4);
    float* x1     = (float*)alloc((size_t)N_NODES * HIDDEN * 4);   // 51.2 MB
    float* agg1   = (float*)alloc((size_t)N_NODES * HIDDEN * 4);   // 51.2 MB (agg1 uses half; agg2 reuses all)
    float* agg2   = agg1;
    float* pooled = (float*)alloc(HIDDEN * 4);

    hipMemsetAsync(deg, 0, (size_t)N_NODES * 4, stream);
    hipMemsetAsync(pooled, 0, HIDDEN * 4, stream);

    hist_kernel<<<(N_EDGES + 255) / 256, 256, 0, stream>>>(dst, deg);
    scan_kernel<<<1, 1024, 0, stream>>>(deg, offsets, cursor);
    scatter_kernel<<<(N_EDGES + 255) / 256, 256, 0, stream>>>(src, dst, cursor, csr_src);

    // layer 1: aggregate node_features (128-dim), then GEMM+relu
    agg_kernel<NODE_DIM><<<(N_NODES * 64) / 256, 256, 0, stream>>>(node_features, offsets, csr_src, agg1);
    gemm1_kernel<<<N_NODES / 16, 256, 0, stream>>>(agg1, W1, b1, x1);

    // layer 2: aggregate x1 (256-dim), then GEMM+relu fused with mean-pool
    agg_kernel<HIDDEN><<<(N_NODES * 64) / 256, 256, 0, stream>>>(x1, offsets, csr_src, agg2);
    gemm2_pool_kernel<<<512, 256, 0, stream>>>(agg2, W2, b2, pooled);

    head_kernel<<<1, 256, 0, stream>>>(pooled, conditions, Wfc, bfc,
                                       Wmean, bmean, Wlogvar, blogvar, out);
}